// Round 3
// baseline (241.508 us; speedup 1.0000x reference)
//
#include <hip/hip_runtime.h>
#include <math.h>

#define BB 256
#define NN 65536
#define NT 1024
#define CAP 2016
#define MARGIN 2e-3f
#define NLC 7   // chunks 0..6 keys cached in LDS; chunks 7..15 REMATERIALIZED per pass

typedef float f32x4 __attribute__((ext_vector_type(4)));

// Monotonic map: float order == uint order (ascending), and inverse
__device__ __forceinline__ unsigned int f2sort(float f) {
    unsigned int b = __float_as_uint(f);
    return (b & 0x80000000u) ? ~b : (b | 0x80000000u);
}
__device__ __forceinline__ float sort2f(unsigned int u) {
    unsigned int b = (u & 0x80000000u) ? (u & 0x7fffffffu) : ~u;
    return __uint_as_float(b);
}

// Bit-exact vs numpy f32 (f64 log rounded to f32) — band + fallback only.
// Deterministic: same inputs -> same bits at every remat site.
__device__ __forceinline__ unsigned int wexact(float u, float d) {
    float t1 = u + 1e-7f;
    float t2 = (float)log((double)t1);
    float t3 = (-t2) + 1e-7f;
    float G  = -(float)log((double)t3);
    float lgD = (float)log((double)d);
    return f2sort(G + lgD);
}

// Fast path: hw v_log_f32. |wfast - wexact| <= ~1.5e-4 abs; MARGIN = 2e-3 gives
// >10x safety. Fallback guards any violation structurally. Deterministic across
// remat sites (fixed instruction sequence, no FMA contraction opportunities).
__device__ __forceinline__ unsigned int wfast(float u, float d) {
    float t1 = u + 1e-7f;
    float t3 = -__logf(t1) + 1e-7f;
    float G  = -__logf(t3);
    return f2sort(G + __logf(d));
}

__device__ __forceinline__ bool finite_f(float f) {
    return (__float_as_uint(f) & 0x7f800000u) != 0x7f800000u;
}

#define PASS1SEL(KKV) \
    { const int b0 = tid * 8; unsigned int cs = 0; \
      _Pragma("unroll") for (int i = 0; i < 8; i++) cs += hist[b0 + i]; \
      chunkSum[tid] = cs; } \
    __syncthreads(); \
    if (tid < 64) { \
        const int c0i = lane * 16; unsigned int s = 0; \
        _Pragma("unroll") for (int i = 0; i < 16; i++) s += chunkSum[c0i + i]; \
        unsigned int suf = s; \
        _Pragma("unroll") for (int off = 1; off < 64; off <<= 1) { \
            unsigned int tv = __shfl_down(suf, off); if (lane + off < 64) suf += tv; } \
        unsigned int above = suf - s; \
        if (suf >= (KKV) && above < (KKV)) { \
            unsigned int cum = above; \
            for (int ci = c0i + 15; ci >= c0i; ci--) { \
                unsigned int cch = chunkSum[ci]; \
                if (cum + cch >= (KKV)) { \
                    for (int b = ci * 8 + 7; ; b--) { \
                        unsigned int c2 = hist[b]; \
                        if (cum + c2 >= (KKV)) { s_sel = (unsigned int)b; s_kneed = (KKV) - cum; s_eq = c2; break; } \
                        cum += c2; } \
                    break; } \
                cum += cch; } } } \
    __syncthreads();

#define PASS2SEL(P, KN) \
    if (tid < 64) { \
        const int c0i = lane * 16; unsigned int s = 0; \
        _Pragma("unroll") for (int i = 0; i < 16; i++) s += hist[c0i + i]; \
        unsigned int suf = s; \
        _Pragma("unroll") for (int off = 1; off < 64; off <<= 1) { \
            unsigned int tv = __shfl_down(suf, off); if (lane + off < 64) suf += tv; } \
        unsigned int above = suf - s; \
        if (suf >= (KN) && above < (KN)) { \
            unsigned int cum = above; \
            for (int b = c0i + 15; ; b--) { \
                unsigned int c2 = hist[b]; \
                if (cum + c2 >= (KN)) { s_sel = ((P) << 10) | (unsigned int)b; s_kneed = (KN) - cum; s_eq = c2; break; } \
                cum += c2; } } } \
    __syncthreads();

#define PASS3SEL(P, KN) \
    if (tid < 64) { \
        const int c0i = lane * 8; unsigned int s = 0; \
        _Pragma("unroll") for (int i = 0; i < 8; i++) s += hist[c0i + i]; \
        unsigned int suf = s; \
        _Pragma("unroll") for (int off = 1; off < 64; off <<= 1) { \
            unsigned int tv = __shfl_down(suf, off); if (lane + off < 64) suf += tv; } \
        unsigned int above = suf - s; \
        if (suf >= (KN) && above < (KN)) { \
            unsigned int cum = above; \
            for (int b = c0i + 7; ; b--) { \
                unsigned int c2 = hist[b]; \
                if (cum + c2 >= (KN)) { s_sel = ((P) << 9) | (unsigned int)b; s_kneed = (KN) - cum; s_eq = c2; break; } \
                cum += c2; } } } \
    __syncthreads();

// R2 post-mortem: the allocator pins 1024-thread blocks at 64 VGPRs regardless
// of launch_bounds/waves_per_eu/LDS hints, so ANY >~30-word live set spills to
// scratch (extra WRITE_SIZE matched spilled-words*4B*threads exactly in R1/R2).
// Strategy: keep NO keys in registers. 7 chunks cached in LDS; the other 9 are
// rematerialized from U/D (L2/L3-resident after pass 1; wfast = 3x v_log_f32,
// ~4 us/pass whole-GPU). Runtime loops (unroll 2) cap the scheduler's
// load-hoisting window so live range stays < 64 VGPRs by construction.
__global__ __launch_bounds__(NT, 4)
void md_fused_kernel(const float* __restrict__ Tt,
                     const float* __restrict__ U,
                     const float* __restrict__ D,
                     float* __restrict__ out,     // [B,N] mask
                     float* __restrict__ wout) {  // [B] weights
    const int row = blockIdx.x;
    const int tid = threadIdx.x;
    const int lane = tid & 63;

    const float* Ur = U + (size_t)row * NN;
    const float* Dr = D + (size_t)row * NN;
    float* Or = out + (size_t)row * NN;

    __shared__ uint4 kls[NLC * 1024];         // 114688 B — keys for chunks 0..6
    __shared__ unsigned int hist[8192];       // 32768 B
    __shared__ unsigned int chunkSum[NT];     // 4096 B
    __shared__ int bandIdx[CAP];              // 8064 B
    __shared__ unsigned int s_sel, s_kneed, s_eq;
    __shared__ int s_A, s_bandCnt, s_tiecnt, s_tieidx;

    // bandU used only AFTER the MRG pass consumed kls (fast path) -> alias.
    unsigned int* bandU = (unsigned int*)kls;
    // tielist used only in fallback (bandIdx dead there) -> alias.
    int* tielist = bandIdx;

    // ---- per-thread k; f32 step-for-step like ref ----
    const float t = Tt[row];
    const float pf = (float)M_PI;
    float aa = pf * t;
    float bbv = aa * 0.5f;
    float c0 = (float)cos((double)bbv);
    float r  = 1.0f - c0;
    const int k = (int)(65536.0f * r);
    if (tid == 0) {
        float tadj = t * 0.998f + 0.001f;
        float arg  = (pf * tadj) * 0.5f;
        wout[row] = (float)(0.5 * M_PI) * (float)sin((double)arg);
    }

    if (k <= 0 || k >= NN) {
        const float fill = (k >= NN) ? 1.0f : 0.0f;
        f32x4 f4 = {fill, fill, fill, fill};
        for (int j = 0; j < 16; j++)
            __builtin_nontemporal_store(f4, (f32x4*)(Or + j * 4096 + tid * 4));
        return;
    }
    const unsigned int kk = (unsigned int)k;

    for (int i = tid; i < 8192; i += NT) hist[i] = 0;
    if (tid == 0) { s_A = 0; s_bandCnt = 0; }
    __syncthreads();

    // ---- pass 1: compute fast keys; cache chunks 0..6 in LDS; 13-bit hist ----
#pragma unroll 2
    for (int J = 0; J < 16; ++J) {
        const int e = (J << 12) + (tid << 2);
        float4 u4 = *(const float4*)(Ur + e);
        float4 d4 = *(const float4*)(Dr + e);
        uint4 kv;
        kv.x = wfast(u4.x, d4.x);
        kv.y = wfast(u4.y, d4.y);
        kv.z = wfast(u4.z, d4.z);
        kv.w = wfast(u4.w, d4.w);
        if (J < NLC) kls[(J << 10) + tid] = kv;
        atomicAdd(&hist[kv.x >> 19], 1u);
        atomicAdd(&hist[kv.y >> 19], 1u);
        atomicAdd(&hist[kv.z >> 19], 1u);
        atomicAdd(&hist[kv.w >> 19], 1u);
    }
    __syncthreads();

    PASS1SEL(kk)
    const unsigned int p13 = s_sel;
    const unsigned int kn1 = s_kneed;
    hist[tid] = 0;
    __syncthreads();

    // ---- pass 2: 10-bit refinement hist within selected 13-bit bucket ----
#pragma unroll 2
    for (int J = 0; J < 16; ++J) {
        uint4 kv;
        if (J < NLC) {
            kv = kls[(J << 10) + tid];
        } else {
            const int e = (J << 12) + (tid << 2);
            float4 u4 = *(const float4*)(Ur + e);
            float4 d4 = *(const float4*)(Dr + e);
            kv.x = wfast(u4.x, d4.x);
            kv.y = wfast(u4.y, d4.y);
            kv.z = wfast(u4.z, d4.z);
            kv.w = wfast(u4.w, d4.w);
        }
        if ((kv.x >> 19) == p13) atomicAdd(&hist[(kv.x >> 9) & 1023u], 1u);
        if ((kv.y >> 19) == p13) atomicAdd(&hist[(kv.y >> 9) & 1023u], 1u);
        if ((kv.z >> 19) == p13) atomicAdd(&hist[(kv.z >> 9) & 1023u], 1u);
        if ((kv.w >> 19) == p13) atomicAdd(&hist[(kv.w >> 9) & 1023u], 1u);
    }
    __syncthreads();
    PASS2SEL(p13, kn1)

    // ---- band bounds: approx-theta's 512-ulp bucket +/- margin ----
    const unsigned int p23 = s_sel;
    const float loF = sort2f(p23 << 9) - MARGIN;
    const float hiF = sort2f((p23 << 9) | 511u) + MARGIN;
    const bool badBand = !(finite_f(loF) && finite_f(hiF));
    const unsigned int lo_u = f2sort(loF);
    const unsigned int hi_u = f2sort(hiF);

    // ---- merged pass: count definite-ins + gather band indices +
    //      PROVISIONAL mask write (band/below get 0; winners fixed up after) ----
    {
        int cnt = 0;
#pragma unroll 2
        for (int J = 0; J < 16; ++J) {
            const int e = (J << 12) + (tid << 2);
            uint4 kv;
            if (J < NLC) {
                kv = kls[(J << 10) + tid];
            } else {
                float4 u4 = *(const float4*)(Ur + e);
                float4 d4 = *(const float4*)(Dr + e);
                kv.x = wfast(u4.x, d4.x);
                kv.y = wfast(u4.y, d4.y);
                kv.z = wfast(u4.z, d4.z);
                kv.w = wfast(u4.w, d4.w);
            }
            f32x4 m;
#define MRGV(UU, EIDX, MF) { const unsigned int uu = (UU); \
            const bool din = uu > hi_u; cnt += (int)din; MF = din ? 1.0f : 0.0f; \
            if (!din && uu >= lo_u) { \
                int slot = atomicAdd(&s_bandCnt, 1); \
                if (slot < CAP) bandIdx[slot] = (EIDX); } }
            MRGV(kv.x, e + 0, m.x)
            MRGV(kv.y, e + 1, m.y)
            MRGV(kv.z, e + 2, m.z)
            MRGV(kv.w, e + 3, m.w)
#undef MRGV
            __builtin_nontemporal_store(m, (f32x4*)(Or + e));
        }
#pragma unroll
        for (int off = 32; off >= 1; off >>= 1) cnt += __shfl_down(cnt, off);
        if (lane == 0) atomicAdd(&s_A, cnt);
    }
    __syncthreads();

    const int bandCnt = s_bandCnt;
    const int kb = k - s_A;
    const bool fallback = badBand || (bandCnt > CAP) || (kb < 0) || (kb > bandCnt);

    if (!fallback) {
        // exact re-eval of band elements (kls is dead now; bandU aliases it)
        for (int j = tid; j < bandCnt; j += NT) {
            int idx = bandIdx[j];
            bandU[j] = wexact(Ur[idx], Dr[idx]);
        }
        __syncthreads();
        // stable rank (desc value, asc index); winners scatter 1.0f over the
        // provisional zeros written in the merged pass
        for (int j = tid; j < bandCnt; j += NT) {
            unsigned int me = bandU[j];
            int mi = bandIdx[j];
            int rk = 0;
            for (int i = 0; i < bandCnt; i++) {
                unsigned int o = bandU[i];
                rk += (int)((o > me) || (o == me && bandIdx[i] < mi));
            }
            if (rk < kb) Or[mi] = 1.0f;
        }
        return;
    }

    // ================= exact fallback (uniform branch; rare) =================
    __syncthreads();
    for (int i = tid; i < 8192; i += NT) hist[i] = 0;
    __syncthreads();
#pragma unroll 1
    for (int J = 0; J < 16; ++J) {
        const int e = (J << 12) + (tid << 2);
        float4 u4 = *(const float4*)(Ur + e);
        float4 d4 = *(const float4*)(Dr + e);
        uint4 kv;
        kv.x = wexact(u4.x, d4.x);
        kv.y = wexact(u4.y, d4.y);
        kv.z = wexact(u4.z, d4.z);
        kv.w = wexact(u4.w, d4.w);
        if (J < NLC) kls[(J << 10) + tid] = kv;
        atomicAdd(&hist[kv.x >> 19], 1u);
        atomicAdd(&hist[kv.y >> 19], 1u);
        atomicAdd(&hist[kv.z >> 19], 1u);
        atomicAdd(&hist[kv.w >> 19], 1u);
    }
    __syncthreads();

    PASS1SEL(kk)
    const unsigned int q13 = s_sel;
    const unsigned int en1 = s_kneed;
    hist[tid] = 0;
    __syncthreads();
#pragma unroll 1
    for (int J = 0; J < 16; ++J) {
        uint4 kv;
        if (J < NLC) {
            kv = kls[(J << 10) + tid];
        } else {
            const int e = (J << 12) + (tid << 2);
            float4 u4 = *(const float4*)(Ur + e);
            float4 d4 = *(const float4*)(Dr + e);
            kv.x = wexact(u4.x, d4.x);
            kv.y = wexact(u4.y, d4.y);
            kv.z = wexact(u4.z, d4.z);
            kv.w = wexact(u4.w, d4.w);
        }
        if ((kv.x >> 19) == q13) atomicAdd(&hist[(kv.x >> 9) & 1023u], 1u);
        if ((kv.y >> 19) == q13) atomicAdd(&hist[(kv.y >> 9) & 1023u], 1u);
        if ((kv.z >> 19) == q13) atomicAdd(&hist[(kv.z >> 9) & 1023u], 1u);
        if ((kv.w >> 19) == q13) atomicAdd(&hist[(kv.w >> 9) & 1023u], 1u);
    }
    __syncthreads();
    PASS2SEL(q13, en1)

    const unsigned int q23 = s_sel;
    const unsigned int en2 = s_kneed;
    if (tid < 512) hist[tid] = 0;
    __syncthreads();
#pragma unroll 1
    for (int J = 0; J < 16; ++J) {
        uint4 kv;
        if (J < NLC) {
            kv = kls[(J << 10) + tid];
        } else {
            const int e = (J << 12) + (tid << 2);
            float4 u4 = *(const float4*)(Ur + e);
            float4 d4 = *(const float4*)(Dr + e);
            kv.x = wexact(u4.x, d4.x);
            kv.y = wexact(u4.y, d4.y);
            kv.z = wexact(u4.z, d4.z);
            kv.w = wexact(u4.w, d4.w);
        }
        if ((kv.x >> 9) == q23) atomicAdd(&hist[kv.x & 511u], 1u);
        if ((kv.y >> 9) == q23) atomicAdd(&hist[kv.y & 511u], 1u);
        if ((kv.z >> 9) == q23) atomicAdd(&hist[kv.z & 511u], 1u);
        if ((kv.w >> 9) == q23) atomicAdd(&hist[kv.w & 511u], 1u);
    }
    __syncthreads();
    PASS3SEL(q23, en2)

    const unsigned int theta = s_sel;
    const unsigned int kneedF = s_kneed, eqF = s_eq;
    const bool needOrder = (kneedF < eqF);
    int istar = NN;
    if (needOrder) {
        if (tid == 0) s_tiecnt = 0;
        __syncthreads();
#pragma unroll 1
        for (int J = 0; J < 16; ++J) {
            const int e = (J << 12) + (tid << 2);
            uint4 kv;
            if (J < NLC) {
                kv = kls[(J << 10) + tid];
            } else {
                float4 u4 = *(const float4*)(Ur + e);
                float4 d4 = *(const float4*)(Dr + e);
                kv.x = wexact(u4.x, d4.x);
                kv.y = wexact(u4.y, d4.y);
                kv.z = wexact(u4.z, d4.z);
                kv.w = wexact(u4.w, d4.w);
            }
#define TIEV(UU, EIDX) if ((UU) == theta) { \
                int pos = atomicAdd(&s_tiecnt, 1); \
                if (pos < 1024) tielist[pos] = (EIDX); }
            TIEV(kv.x, e + 0)
            TIEV(kv.y, e + 1)
            TIEV(kv.z, e + 2)
            TIEV(kv.w, e + 3)
#undef TIEV
        }
        __syncthreads();
        if (tid == 0) {
            int E = s_tiecnt; if (E > 1024) E = 1024;
            for (int aI = 1; aI < E; aI++) {
                int val = tielist[aI]; int bI = aI - 1;
                while (bI >= 0 && tielist[bI] > val) { tielist[bI + 1] = tielist[bI]; bI--; }
                tielist[bI + 1] = val;
            }
            int kk2 = (int)kneedF; if (kk2 > E) kk2 = E; if (kk2 < 1) kk2 = 1;
            s_tieidx = tielist[kk2 - 1];
        }
        __syncthreads();
        istar = s_tieidx;
    }

#pragma unroll 1
    for (int J = 0; J < 16; ++J) {
        const int e = (J << 12) + (tid << 2);
        uint4 kv;
        if (J < NLC) {
            kv = kls[(J << 10) + tid];
        } else {
            float4 u4 = *(const float4*)(Ur + e);
            float4 d4 = *(const float4*)(Dr + e);
            kv.x = wexact(u4.x, d4.x);
            kv.y = wexact(u4.y, d4.y);
            kv.z = wexact(u4.z, d4.z);
            kv.w = wexact(u4.w, d4.w);
        }
        f32x4 m;
#define MVE(u, idx) ((((u) > theta) || ((u) == theta && (!needOrder || (idx) <= istar))) ? 1.0f : 0.0f)
        m.x = MVE(kv.x, e + 0);
        m.y = MVE(kv.y, e + 1);
        m.z = MVE(kv.z, e + 2);
        m.w = MVE(kv.w, e + 3);
#undef MVE
        __builtin_nontemporal_store(m, (f32x4*)(Or + e));
    }
}

extern "C" void kernel_launch(void* const* d_in, const int* in_sizes, int n_in,
                              void* d_out, int out_size, void* d_ws, size_t ws_size,
                              hipStream_t stream) {
    // inputs: batch[B*N] i32 (unused), t[B] f32, U[B*N] f32, D[B*N] f32
    const float* T = (const float*)d_in[1];
    const float* U = (const float*)d_in[2];
    const float* D = (const float*)d_in[3];
    float* out = (float*)d_out;
    float* wout = out + (size_t)BB * NN;

    md_fused_kernel<<<BB, NT, 0, stream>>>(T, U, D, out, wout);
}

// Round 4
// 233.519 us; speedup vs baseline: 1.0342x; 1.0342x over previous
//
#include <hip/hip_runtime.h>
#include <math.h>

#define BB 256
#define NN 65536
#define NT 1024
#define CAP 2016
#define MARGIN 2e-3f

typedef float f32x4 __attribute__((ext_vector_type(4)));
typedef unsigned int u32x4 __attribute__((ext_vector_type(4)));

#define ONE_BITS 0x3F800000u   // bit pattern of 1.0f

// Monotonic map: float order == uint order (ascending), and inverse
__device__ __forceinline__ unsigned int f2sort(float f) {
    unsigned int b = __float_as_uint(f);
    return (b & 0x80000000u) ? ~b : (b | 0x80000000u);
}
__device__ __forceinline__ float sort2f(unsigned int u) {
    unsigned int b = (u & 0x80000000u) ? (u & 0x7fffffffu) : ~u;
    return __uint_as_float(b);
}

// Bit-exact vs numpy f32 (f64 log rounded to f32) — band + fallback only.
__device__ __forceinline__ unsigned int wexact(float u, float d) {
    float t1 = u + 1e-7f;
    float t2 = (float)log((double)t1);
    float t3 = (-t2) + 1e-7f;
    float G  = -(float)log((double)t3);
    float lgD = (float)log((double)d);
    return f2sort(G + lgD);
}

// Fast path: hw v_log_f32. |wfast - wexact| <= ~1.5e-4 abs; MARGIN = 2e-3 gives
// >10x safety. Fallback guards any violation structurally.
__device__ __forceinline__ unsigned int wfast(float u, float d) {
    float t1 = u + 1e-7f;
    float t3 = -__logf(t1) + 1e-7f;
    float G  = -__logf(t3);
    return f2sort(G + __logf(d));
}

__device__ __forceinline__ bool finite_f(float f) {
    return (__float_as_uint(f) & 0x7f800000u) != 0x7f800000u;
}

#define PASS1SEL(KKV) \
    { const int b0 = tid * 8; unsigned int cs = 0; \
      _Pragma("unroll") for (int i = 0; i < 8; i++) cs += hist[b0 + i]; \
      chunkSum[tid] = cs; } \
    __syncthreads(); \
    if (tid < 64) { \
        const int c0i = lane * 16; unsigned int s = 0; \
        _Pragma("unroll") for (int i = 0; i < 16; i++) s += chunkSum[c0i + i]; \
        unsigned int suf = s; \
        _Pragma("unroll") for (int off = 1; off < 64; off <<= 1) { \
            unsigned int tv = __shfl_down(suf, off); if (lane + off < 64) suf += tv; } \
        unsigned int above = suf - s; \
        if (suf >= (KKV) && above < (KKV)) { \
            unsigned int cum = above; \
            for (int ci = c0i + 15; ci >= c0i; ci--) { \
                unsigned int cch = chunkSum[ci]; \
                if (cum + cch >= (KKV)) { \
                    for (int b = ci * 8 + 7; ; b--) { \
                        unsigned int c2 = hist[b]; \
                        if (cum + c2 >= (KKV)) { s_sel = (unsigned int)b; s_kneed = (KKV) - cum; s_eq = c2; break; } \
                        cum += c2; } \
                    break; } \
                cum += cch; } } } \
    __syncthreads();

#define PASS2SEL(P, KN) \
    if (tid < 64) { \
        const int c0i = lane * 16; unsigned int s = 0; \
        _Pragma("unroll") for (int i = 0; i < 16; i++) s += hist[c0i + i]; \
        unsigned int suf = s; \
        _Pragma("unroll") for (int off = 1; off < 64; off <<= 1) { \
            unsigned int tv = __shfl_down(suf, off); if (lane + off < 64) suf += tv; } \
        unsigned int above = suf - s; \
        if (suf >= (KN) && above < (KN)) { \
            unsigned int cum = above; \
            for (int b = c0i + 15; ; b--) { \
                unsigned int c2 = hist[b]; \
                if (cum + c2 >= (KN)) { s_sel = ((P) << 10) | (unsigned int)b; s_kneed = (KN) - cum; s_eq = c2; break; } \
                cum += c2; } } } \
    __syncthreads();

#define PASS3SEL(P, KN) \
    if (tid < 64) { \
        const int c0i = lane * 8; unsigned int s = 0; \
        _Pragma("unroll") for (int i = 0; i < 8; i++) s += hist[c0i + i]; \
        unsigned int suf = s; \
        _Pragma("unroll") for (int off = 1; off < 64; off <<= 1) { \
            unsigned int tv = __shfl_down(suf, off); if (lane + off < 64) suf += tv; } \
        unsigned int above = suf - s; \
        if (suf >= (KN) && above < (KN)) { \
            unsigned int cum = above; \
            for (int b = c0i + 7; ; b--) { \
                unsigned int c2 = hist[b]; \
                if (cum + c2 >= (KN)) { s_sel = ((P) << 9) | (unsigned int)b; s_kneed = (KN) - cum; s_eq = c2; break; } \
                cum += c2; } } } \
    __syncthreads();

// R3 post-mortem: remat fixed the spill (WRITE=ideal 66 MB, VGPR 52) but moved
// the cost to FETCH (140 MB input re-reads) + VALU (47%, 3x wfast passes).
// R4: keys live in the OUTPUT buffer (dead space until final write). Pass 1
// stores keys -> Or (cached, L2/L3-resident); P2/MRG stream them back (4 B/key
// vs 8 B U+D re-read + 3 transcendentals); MRG overwrites keys with the mask
// (same thread, same address). All Or accesses are uint-typed (mask stored as
// 0x3F800000/0 bit patterns) to avoid TBAA load/store reordering at the same
// address. Band exactness + fallback logic byte-identical to validated R3.
__global__ __launch_bounds__(NT, 4)
void md_fused_kernel(const float* __restrict__ Tt,
                     const float* __restrict__ U,
                     const float* __restrict__ D,
                     float* __restrict__ out,     // [B,N] mask (also key scratch)
                     float* __restrict__ wout) {  // [B] weights
    const int row = blockIdx.x;
    const int tid = threadIdx.x;
    const int lane = tid & 63;

    const float* Ur = U + (size_t)row * NN;
    const float* Dr = D + (size_t)row * NN;
    unsigned int* OrU = (unsigned int*)out + (size_t)row * NN;

    __shared__ unsigned int hist[8192];       // 32 KB
    __shared__ unsigned int chunkSum[NT];     // 4 KB
    __shared__ unsigned int bandU[CAP];       // 8 KB
    __shared__ int bandIdx[CAP];              // 8 KB
    __shared__ unsigned int s_sel, s_kneed, s_eq;
    __shared__ int s_A, s_bandCnt, s_tiecnt, s_tieidx;

    // tielist used only in fallback (bandIdx dead there) -> alias.
    int* tielist = bandIdx;

    // ---- per-thread k; f32 step-for-step like ref ----
    const float t = Tt[row];
    const float pf = (float)M_PI;
    float aa = pf * t;
    float bbv = aa * 0.5f;
    float c0 = (float)cos((double)bbv);
    float r  = 1.0f - c0;
    const int k = (int)(65536.0f * r);
    if (tid == 0) {
        float tadj = t * 0.998f + 0.001f;
        float arg  = (pf * tadj) * 0.5f;
        wout[row] = (float)(0.5 * M_PI) * (float)sin((double)arg);
    }

    if (k <= 0 || k >= NN) {
        const unsigned int fb = (k >= NN) ? ONE_BITS : 0u;
        u32x4 f4 = {fb, fb, fb, fb};
        for (int j = 0; j < 16; j++)
            __builtin_nontemporal_store(f4, (u32x4*)(OrU + j * 4096 + tid * 4));
        return;
    }
    const unsigned int kk = (unsigned int)k;

    for (int i = tid; i < 8192; i += NT) hist[i] = 0;
    if (tid == 0) { s_A = 0; s_bandCnt = 0; }
    __syncthreads();

    // ---- pass 1: read U,D once; wfast keys -> Or (cached stores); 13-bit hist ----
#pragma unroll 2
    for (int J = 0; J < 16; ++J) {
        const int e = (J << 12) + (tid << 2);
        float4 u4 = *(const float4*)(Ur + e);
        float4 d4 = *(const float4*)(Dr + e);
        u32x4 kv;
        kv.x = wfast(u4.x, d4.x);
        kv.y = wfast(u4.y, d4.y);
        kv.z = wfast(u4.z, d4.z);
        kv.w = wfast(u4.w, d4.w);
        *(u32x4*)(OrU + e) = kv;          // NORMAL store: keep hot for P2/MRG
        atomicAdd(&hist[kv.x >> 19], 1u);
        atomicAdd(&hist[kv.y >> 19], 1u);
        atomicAdd(&hist[kv.z >> 19], 1u);
        atomicAdd(&hist[kv.w >> 19], 1u);
    }
    __syncthreads();

    PASS1SEL(kk)
    const unsigned int p13 = s_sel;
    const unsigned int kn1 = s_kneed;
    hist[tid] = 0;
    __syncthreads();

    // ---- pass 2: stream keys back; 10-bit refinement hist ----
#pragma unroll 2
    for (int J = 0; J < 16; ++J) {
        const int e = (J << 12) + (tid << 2);
        u32x4 kv = *(const u32x4*)(OrU + e);
        if ((kv.x >> 19) == p13) atomicAdd(&hist[(kv.x >> 9) & 1023u], 1u);
        if ((kv.y >> 19) == p13) atomicAdd(&hist[(kv.y >> 9) & 1023u], 1u);
        if ((kv.z >> 19) == p13) atomicAdd(&hist[(kv.z >> 9) & 1023u], 1u);
        if ((kv.w >> 19) == p13) atomicAdd(&hist[(kv.w >> 9) & 1023u], 1u);
    }
    __syncthreads();
    PASS2SEL(p13, kn1)

    // ---- band bounds: approx-theta's 512-ulp bucket +/- margin ----
    const unsigned int p23 = s_sel;
    const float loF = sort2f(p23 << 9) - MARGIN;
    const float hiF = sort2f((p23 << 9) | 511u) + MARGIN;
    const bool badBand = !(finite_f(loF) && finite_f(hiF));
    const unsigned int lo_u = f2sort(loF);
    const unsigned int hi_u = f2sort(hiF);

    // ---- merged pass: stream keys (nt load, last use) -> classify, count
    //      definite-ins, gather band indices, OVERWRITE key with provisional
    //      mask (same thread, same address; uint-typed both ways) ----
    {
        int cnt = 0;
#pragma unroll 2
        for (int J = 0; J < 16; ++J) {
            const int e = (J << 12) + (tid << 2);
            u32x4 kv = __builtin_nontemporal_load((const u32x4*)(OrU + e));
            u32x4 m;
#define MRGV(UU, EIDX, MF) { const unsigned int uu = (UU); \
            const bool din = uu > hi_u; cnt += (int)din; MF = din ? ONE_BITS : 0u; \
            if (!din && uu >= lo_u) { \
                int slot = atomicAdd(&s_bandCnt, 1); \
                if (slot < CAP) bandIdx[slot] = (EIDX); } }
            MRGV(kv.x, e + 0, m.x)
            MRGV(kv.y, e + 1, m.y)
            MRGV(kv.z, e + 2, m.z)
            MRGV(kv.w, e + 3, m.w)
#undef MRGV
            __builtin_nontemporal_store(m, (u32x4*)(OrU + e));
        }
#pragma unroll
        for (int off = 32; off >= 1; off >>= 1) cnt += __shfl_down(cnt, off);
        if (lane == 0) atomicAdd(&s_A, cnt);
    }
    __syncthreads();

    const int bandCnt = s_bandCnt;
    const int kb = k - s_A;
    const bool fallback = badBand || (bandCnt > CAP) || (kb < 0) || (kb > bandCnt);

    if (!fallback) {
        // exact re-eval of band elements from U/D (keys in Or already destroyed)
        for (int j = tid; j < bandCnt; j += NT) {
            int idx = bandIdx[j];
            bandU[j] = wexact(Ur[idx], Dr[idx]);
        }
        __syncthreads();
        // stable rank (desc value, asc index); winners scatter 1.0 over the
        // provisional zeros written in the merged pass
        for (int j = tid; j < bandCnt; j += NT) {
            unsigned int me = bandU[j];
            int mi = bandIdx[j];
            int rk = 0;
            for (int i = 0; i < bandCnt; i++) {
                unsigned int o = bandU[i];
                rk += (int)((o > me) || (o == me && bandIdx[i] < mi));
            }
            if (rk < kb) OrU[mi] = ONE_BITS;
        }
        return;
    }

    // ================= exact fallback (uniform branch; rare) =================
    // Rebuild exact keys into Or from U/D, then radix P1/P2/P3 + tie + write.
    __syncthreads();
    for (int i = tid; i < 8192; i += NT) hist[i] = 0;
    __syncthreads();
#pragma unroll 1
    for (int J = 0; J < 16; ++J) {
        const int e = (J << 12) + (tid << 2);
        float4 u4 = *(const float4*)(Ur + e);
        float4 d4 = *(const float4*)(Dr + e);
        u32x4 kv;
        kv.x = wexact(u4.x, d4.x);
        kv.y = wexact(u4.y, d4.y);
        kv.z = wexact(u4.z, d4.z);
        kv.w = wexact(u4.w, d4.w);
        *(u32x4*)(OrU + e) = kv;
        atomicAdd(&hist[kv.x >> 19], 1u);
        atomicAdd(&hist[kv.y >> 19], 1u);
        atomicAdd(&hist[kv.z >> 19], 1u);
        atomicAdd(&hist[kv.w >> 19], 1u);
    }
    __syncthreads();

    PASS1SEL(kk)
    const unsigned int q13 = s_sel;
    const unsigned int en1 = s_kneed;
    hist[tid] = 0;
    __syncthreads();
#pragma unroll 1
    for (int J = 0; J < 16; ++J) {
        const int e = (J << 12) + (tid << 2);
        u32x4 kv = *(const u32x4*)(OrU + e);
        if ((kv.x >> 19) == q13) atomicAdd(&hist[(kv.x >> 9) & 1023u], 1u);
        if ((kv.y >> 19) == q13) atomicAdd(&hist[(kv.y >> 9) & 1023u], 1u);
        if ((kv.z >> 19) == q13) atomicAdd(&hist[(kv.z >> 9) & 1023u], 1u);
        if ((kv.w >> 19) == q13) atomicAdd(&hist[(kv.w >> 9) & 1023u], 1u);
    }
    __syncthreads();
    PASS2SEL(q13, en1)

    const unsigned int q23 = s_sel;
    const unsigned int en2 = s_kneed;
    if (tid < 512) hist[tid] = 0;
    __syncthreads();
#pragma unroll 1
    for (int J = 0; J < 16; ++J) {
        const int e = (J << 12) + (tid << 2);
        u32x4 kv = *(const u32x4*)(OrU + e);
        if ((kv.x >> 9) == q23) atomicAdd(&hist[kv.x & 511u], 1u);
        if ((kv.y >> 9) == q23) atomicAdd(&hist[kv.y & 511u], 1u);
        if ((kv.z >> 9) == q23) atomicAdd(&hist[kv.z & 511u], 1u);
        if ((kv.w >> 9) == q23) atomicAdd(&hist[kv.w & 511u], 1u);
    }
    __syncthreads();
    PASS3SEL(q23, en2)

    const unsigned int theta = s_sel;
    const unsigned int kneedF = s_kneed, eqF = s_eq;
    const bool needOrder = (kneedF < eqF);
    int istar = NN;
    if (needOrder) {
        if (tid == 0) s_tiecnt = 0;
        __syncthreads();
#pragma unroll 1
        for (int J = 0; J < 16; ++J) {
            const int e = (J << 12) + (tid << 2);
            u32x4 kv = *(const u32x4*)(OrU + e);
#define TIEV(UU, EIDX) if ((UU) == theta) { \
                int pos = atomicAdd(&s_tiecnt, 1); \
                if (pos < 1024) tielist[pos] = (EIDX); }
            TIEV(kv.x, e + 0)
            TIEV(kv.y, e + 1)
            TIEV(kv.z, e + 2)
            TIEV(kv.w, e + 3)
#undef TIEV
        }
        __syncthreads();
        if (tid == 0) {
            int E = s_tiecnt; if (E > 1024) E = 1024;
            for (int aI = 1; aI < E; aI++) {
                int val = tielist[aI]; int bI = aI - 1;
                while (bI >= 0 && tielist[bI] > val) { tielist[bI + 1] = tielist[bI]; bI--; }
                tielist[bI + 1] = val;
            }
            int kk2 = (int)kneedF; if (kk2 > E) kk2 = E; if (kk2 < 1) kk2 = 1;
            s_tieidx = tielist[kk2 - 1];
        }
        __syncthreads();
        istar = s_tieidx;
    }

#pragma unroll 1
    for (int J = 0; J < 16; ++J) {
        const int e = (J << 12) + (tid << 2);
        u32x4 kv = __builtin_nontemporal_load((const u32x4*)(OrU + e));
        u32x4 m;
#define MVE(u, idx) ((((u) > theta) || ((u) == theta && (!needOrder || (idx) <= istar))) ? ONE_BITS : 0u)
        m.x = MVE(kv.x, e + 0);
        m.y = MVE(kv.y, e + 1);
        m.z = MVE(kv.z, e + 2);
        m.w = MVE(kv.w, e + 3);
#undef MVE
        __builtin_nontemporal_store(m, (u32x4*)(OrU + e));
    }
}

extern "C" void kernel_launch(void* const* d_in, const int* in_sizes, int n_in,
                              void* d_out, int out_size, void* d_ws, size_t ws_size,
                              hipStream_t stream) {
    // inputs: batch[B*N] i32 (unused), t[B] f32, U[B*N] f32, D[B*N] f32
    const float* T = (const float*)d_in[1];
    const float* U = (const float*)d_in[2];
    const float* D = (const float*)d_in[3];
    float* out = (float*)d_out;
    float* wout = out + (size_t)BB * NN;

    md_fused_kernel<<<BB, NT, 0, stream>>>(T, U, D, out, wout);
}

// Round 5
// 230.423 us; speedup vs baseline: 1.0481x; 1.0134x over previous
//
#include <hip/hip_runtime.h>
#include <math.h>

#define BB 256
#define NN 65536
#define NT 1024
#define SM 4096        // samples per row (first SM elements; Dirichlet rows exchangeable)
#define RANKPAD 160    // ~5-sigma sample-rank cushion (miss prob ~4e-6/row -> fallback)
#define CAPC 8192      // candidate capacity (expected ~5300)
#define CAPB 2048      // micro-band capacity (old validated CAP was 2016)
#define QMARG 2e-3f    // relative q-space margin == validated 2e-3 w-space margin

typedef float f32x4 __attribute__((ext_vector_type(4)));
typedef unsigned int u32x4 __attribute__((ext_vector_type(4)));

#define ONE_BITS 0x3F800000u   // bit pattern of 1.0f

// Monotonic map: float order == uint order (ascending), and inverse
__device__ __forceinline__ unsigned int f2sort(float f) {
    unsigned int b = __float_as_uint(f);
    return (b & 0x80000000u) ? ~b : (b | 0x80000000u);
}
__device__ __forceinline__ float sort2f(unsigned int u) {
    unsigned int b = (u & 0x80000000u) ? (u & 0x7fffffffu) : ~u;
    return __uint_as_float(b);
}

// Bit-exact vs numpy f32 (f64 log rounded to f32) — band + fallback only.
__device__ __forceinline__ unsigned int wexact(float u, float d) {
    float t1 = u + 1e-7f;
    float t2 = (float)log((double)t1);
    float t3 = (-t2) + 1e-7f;
    float G  = -(float)log((double)t3);
    float lgD = (float)log((double)d);
    return f2sort(G + lgD);
}

// Order-equivalent fast key: w = ln(d/t3)  =>  rank by q = d/t3 directly.
// ONE v_log + v_rcp instead of 3 logs. |ln(q_fast) - w_exact| <= ~1.6e-4
// (t3 rel error bound validated by 5 rounds of wfast at MARGIN 2e-3);
// QMARG 2e-3 rel gives >10x cushion; fallback guards structurally.
__device__ __forceinline__ unsigned int qkey(float u, float d) {
    float t3 = 1e-7f - __logf(u + 1e-7f);           // > 0 always (u < 1)
    float q  = d * __builtin_amdgcn_rcpf(t3);       // >= +0, <= ~1.1e7
    return f2sort(q);
}

__device__ __forceinline__ bool finite_f(float f) {
    return (__float_as_uint(f) & 0x7f800000u) != 0x7f800000u;
}

#define PASS1SEL(KKV) \
    { const int b0 = tid * 8; unsigned int cs = 0; \
      _Pragma("unroll") for (int i = 0; i < 8; i++) cs += hist[b0 + i]; \
      chunkSum[tid] = cs; } \
    __syncthreads(); \
    if (tid < 64) { \
        const int c0i = lane * 16; unsigned int s = 0; \
        _Pragma("unroll") for (int i = 0; i < 16; i++) s += chunkSum[c0i + i]; \
        unsigned int suf = s; \
        _Pragma("unroll") for (int off = 1; off < 64; off <<= 1) { \
            unsigned int tv = __shfl_down(suf, off); if (lane + off < 64) suf += tv; } \
        unsigned int above = suf - s; \
        if (suf >= (KKV) && above < (KKV)) { \
            unsigned int cum = above; \
            for (int ci = c0i + 15; ci >= c0i; ci--) { \
                unsigned int cch = chunkSum[ci]; \
                if (cum + cch >= (KKV)) { \
                    for (int b = ci * 8 + 7; ; b--) { \
                        unsigned int c2 = hist[b]; \
                        if (cum + c2 >= (KKV)) { s_sel = (unsigned int)b; s_kneed = (KKV) - cum; s_eq = c2; break; } \
                        cum += c2; } \
                    break; } \
                cum += cch; } } } \
    __syncthreads();

#define PASS2SEL(P, KN) \
    if (tid < 64) { \
        const int c0i = lane * 16; unsigned int s = 0; \
        _Pragma("unroll") for (int i = 0; i < 16; i++) s += hist[c0i + i]; \
        unsigned int suf = s; \
        _Pragma("unroll") for (int off = 1; off < 64; off <<= 1) { \
            unsigned int tv = __shfl_down(suf, off); if (lane + off < 64) suf += tv; } \
        unsigned int above = suf - s; \
        if (suf >= (KN) && above < (KN)) { \
            unsigned int cum = above; \
            for (int b = c0i + 15; ; b--) { \
                unsigned int c2 = hist[b]; \
                if (cum + c2 >= (KN)) { s_sel = ((P) << 10) | (unsigned int)b; s_kneed = (KN) - cum; s_eq = c2; break; } \
                cum += c2; } } } \
    __syncthreads();

#define PASS3SEL(P, KN) \
    if (tid < 64) { \
        const int c0i = lane * 8; unsigned int s = 0; \
        _Pragma("unroll") for (int i = 0; i < 8; i++) s += hist[c0i + i]; \
        unsigned int suf = s; \
        _Pragma("unroll") for (int off = 1; off < 64; off <<= 1) { \
            unsigned int tv = __shfl_down(suf, off); if (lane + off < 64) suf += tv; } \
        unsigned int above = suf - s; \
        if (suf >= (KN) && above < (KN)) { \
            unsigned int cum = above; \
            for (int b = c0i + 7; ; b--) { \
                unsigned int c2 = hist[b]; \
                if (cum + c2 >= (KN)) { s_sel = ((P) << 9) | (unsigned int)b; s_kneed = (KN) - cum; s_eq = c2; break; } \
                cum += c2; } } } \
    __syncthreads();

// R4 post-mortem: the 64 keys/thread cost the same wherever stored (scratch/
// LDS/out). R5: never store them. Sample 4096 elements -> value pivots at rank
// k +/- 2560; ONE streaming pass classifies vs pivots, writes provisional mask,
// gathers ~5K candidates to LDS; selection + exact micro-band all-LDS.
__global__ __launch_bounds__(NT, 4)
void md_fused_kernel(const float* __restrict__ Tt,
                     const float* __restrict__ U,
                     const float* __restrict__ D,
                     float* __restrict__ out,     // [B,N] mask
                     float* __restrict__ wout) {  // [B] weights
    const int row = blockIdx.x;
    const int tid = threadIdx.x;
    const int lane = tid & 63;

    const float* Ur = U + (size_t)row * NN;
    const float* Dr = D + (size_t)row * NN;
    unsigned int* OrU = (unsigned int*)out + (size_t)row * NN;

    __shared__ unsigned int hist[8192];       // 32 KB
    __shared__ unsigned int chunkSum[NT];     // 4 KB
    __shared__ unsigned int skey[SM];         // 16 KB; dead after pivots
    __shared__ unsigned int candKey[CAPC];    // 32 KB
    __shared__ int candIdx[CAPC];             // 32 KB
    __shared__ unsigned int s_sel, s_kneed, s_eq;
    __shared__ int s_A, s_candCnt, s_bandCnt, s_above, s_tiecnt, s_tieidx;

    // micro-band aliases the dead sample buffer (2048+2048 = 4096 words)
    unsigned int* bandU = skey;               // [CAPB]
    int* bandIdxA = (int*)(skey + CAPB);      // [CAPB]
    // fallback-only alias (candidates dead there)
    int* tielist = candIdx;

    // ---- per-thread k; f32 step-for-step like ref ----
    const float t = Tt[row];
    const float pf = (float)M_PI;
    float aa = pf * t;
    float bbv = aa * 0.5f;
    float c0 = (float)cos((double)bbv);
    float r  = 1.0f - c0;
    const int k = (int)(65536.0f * r);
    if (tid == 0) {
        float tadj = t * 0.998f + 0.001f;
        float arg  = (pf * tadj) * 0.5f;
        wout[row] = (float)(0.5 * M_PI) * (float)sin((double)arg);
    }

    if (k <= 0 || k >= NN) {
        const unsigned int fbv = (k >= NN) ? ONE_BITS : 0u;
        u32x4 f4 = {fbv, fbv, fbv, fbv};
        for (int j = 0; j < 16; j++)
            __builtin_nontemporal_store(f4, (u32x4*)(OrU + j * 4096 + tid * 4));
        return;
    }
    const unsigned int kk = (unsigned int)k;

    // ================= sample phase: pivots at rank k -/+ RANKPAD*16 ========
    for (int i = tid; i < 8192; i += NT) hist[i] = 0;
    if (tid == 0) { s_A = 0; s_candCnt = 0; s_bandCnt = 0; s_above = 0; }
    __syncthreads();
    {
        float4 u4 = *(const float4*)(Ur + (tid << 2));
        float4 d4 = *(const float4*)(Dr + (tid << 2));
        unsigned int s0 = qkey(u4.x, d4.x), s1 = qkey(u4.y, d4.y);
        unsigned int s2 = qkey(u4.z, d4.z), s3 = qkey(u4.w, d4.w);
        skey[(tid << 2) + 0] = s0; skey[(tid << 2) + 1] = s1;
        skey[(tid << 2) + 2] = s2; skey[(tid << 2) + 3] = s3;
        atomicAdd(&hist[s0 >> 19], 1u); atomicAdd(&hist[s1 >> 19], 1u);
        atomicAdd(&hist[s2 >> 19], 1u); atomicAdd(&hist[s3 >> 19], 1u);
    }
    __syncthreads();

    const int rh = (k >> 4) - RANKPAD;
    unsigned int hi_pivot_u = 0xFFFFFFFFu;    // inactive: nothing definite-in
    if (rh >= 1) {
        PASS1SEL((unsigned int)rh)
        const unsigned int bh = s_sel; const unsigned int knh = s_kneed;
        hist[tid] = 0;
        __syncthreads();
        for (int j = tid; j < SM; j += NT) { unsigned int sk = skey[j];
            if ((sk >> 19) == bh) atomicAdd(&hist[(sk >> 9) & 1023u], 1u); }
        __syncthreads();
        PASS2SEL(bh, knh)
        hi_pivot_u = (s_sel << 9) | 0x1FFu;   // TOP edge of 512-ulp bucket
        // rebuild full sample hist for the lo selection
        for (int i = tid; i < 8192; i += NT) hist[i] = 0;
        __syncthreads();
        for (int j = tid; j < SM; j += NT) atomicAdd(&hist[skey[j] >> 19], 1u);
        __syncthreads();
    }

    const int rl = ((k + 15) >> 4) + RANKPAD;
    unsigned int lo_pivot_u = 0u;             // inactive: everything candidate
    if (rl <= SM) {
        PASS1SEL((unsigned int)rl)
        const unsigned int bl = s_sel; const unsigned int knl = s_kneed;
        hist[tid] = 0;
        __syncthreads();
        for (int j = tid; j < SM; j += NT) { unsigned int sk = skey[j];
            if ((sk >> 19) == bl) atomicAdd(&hist[(sk >> 9) & 1023u], 1u); }
        __syncthreads();
        PASS2SEL(bl, knl)
        lo_pivot_u = (s_sel << 9);            // LOWER edge of 512-ulp bucket
    }
    __syncthreads();

    // ================= THE single streaming pass ============================
    {
        int cntA = 0;
#pragma unroll 2
        for (int J = 0; J < 16; ++J) {
            const int e = (J << 12) + (tid << 2);
            float4 u4 = *(const float4*)(Ur + e);
            float4 d4 = *(const float4*)(Dr + e);
            u32x4 kv;
            kv.x = qkey(u4.x, d4.x); kv.y = qkey(u4.y, d4.y);
            kv.z = qkey(u4.z, d4.z); kv.w = qkey(u4.w, d4.w);
            u32x4 m;
#define MPROC(KC, CI, MF) { \
            const unsigned int qv = (KC); \
            const bool din = qv > hi_pivot_u; \
            cntA += (int)din; MF = din ? ONE_BITS : 0u; \
            const bool isc = (!din) && (qv > lo_pivot_u); \
            const unsigned long long mb = __ballot(isc); \
            if (mb) { \
                const int ldr = __ffsll((unsigned long long)mb) - 1; \
                int wbase = 0; \
                if (lane == ldr) wbase = atomicAdd(&s_candCnt, __popcll(mb)); \
                wbase = __shfl(wbase, ldr); \
                if (isc) { \
                    const int slot = wbase + __popcll(mb & ((1ull << lane) - 1ull)); \
                    if (slot < CAPC) { candKey[slot] = qv; candIdx[slot] = e + (CI); } \
                } } }
            MPROC(kv.x, 0, m.x)
            MPROC(kv.y, 1, m.y)
            MPROC(kv.z, 2, m.z)
            MPROC(kv.w, 3, m.w)
#undef MPROC
            *(u32x4*)(OrU + e) = m;   // cached store: scatter fix-ups hit L2/L3
        }
#pragma unroll
        for (int off = 32; off >= 1; off >>= 1) cntA += __shfl_down(cntA, off);
        if (lane == 0) atomicAdd(&s_A, cntA);
    }
    __syncthreads();

    const int candCnt0 = s_candCnt;
    const int candCnt = candCnt0 > CAPC ? CAPC : candCnt0;
    const int kb = k - s_A;
    bool fb = (candCnt0 > CAPC) || (kb < 1) || (kb > candCnt0);

    // ================= candidate selection (all-LDS) ========================
    unsigned int theta_q = 0, band_lo_u = 0, band_hi_u = 0;
    if (!fb) {
        for (int i = tid; i < 8192; i += NT) hist[i] = 0;
        __syncthreads();
        for (int j = tid; j < candCnt; j += NT) atomicAdd(&hist[candKey[j] >> 19], 1u);
        __syncthreads();
        PASS1SEL((unsigned int)kb)
        const unsigned int c13 = s_sel; const unsigned int ck1 = s_kneed;
        hist[tid] = 0;
        __syncthreads();
        for (int j = tid; j < candCnt; j += NT) { unsigned int ck = candKey[j];
            if ((ck >> 19) == c13) atomicAdd(&hist[(ck >> 9) & 1023u], 1u); }
        __syncthreads();
        PASS2SEL(c13, ck1)
        const unsigned int c23 = s_sel; const unsigned int ck2 = s_kneed;
        if (tid < 512) hist[tid] = 0;
        __syncthreads();
        for (int j = tid; j < candCnt; j += NT) { unsigned int ck = candKey[j];
            if ((ck >> 9) == c23) atomicAdd(&hist[ck & 511u], 1u); }
        __syncthreads();
        PASS3SEL(c23, ck2)
        theta_q = s_sel;

        const float theta_f = sort2f(theta_q);
        band_lo_u = f2sort(theta_f * (1.0f - QMARG));
        band_hi_u = f2sort(theta_f * (1.0f + QMARG));
        { const unsigned int fl = (theta_q >= 0x80000100u) ? (theta_q - 256u) : 0x80000000u;
          if (band_lo_u > fl) band_lo_u = fl;
          const unsigned int fh = theta_q + 256u;
          if (band_hi_u < fh) band_hi_u = fh; }
        // margin zone must lie strictly inside (lo_pivot, hi_pivot]
        fb = !(finite_f(theta_f)) || !(band_hi_u < hi_pivot_u) || !(band_lo_u > lo_pivot_u);
    }

    if (!fb) {
        int ab = 0;
        for (int j = tid; j < candCnt; j += NT) {
            const unsigned int ck = candKey[j];
            if (ck > band_hi_u) ab++;
            else if (ck >= band_lo_u) {
                const int slot = atomicAdd(&s_bandCnt, 1);
                if (slot < CAPB) bandIdxA[slot] = candIdx[j];
            }
        }
#pragma unroll
        for (int off = 32; off >= 1; off >>= 1) ab += __shfl_down(ab, off);
        if (lane == 0) atomicAdd(&s_above, ab);
        __syncthreads();
        const int bandCnt = s_bandCnt;
        const int kb2 = kb - s_above;
        fb = (bandCnt > CAPB) || (kb2 < 0) || (kb2 > bandCnt);

        if (!fb) {
            // exact re-eval of micro-band (scattered, tiny, L3-hot)
            for (int j = tid; j < bandCnt; j += NT) {
                const int idx = bandIdxA[j];
                bandU[j] = wexact(Ur[idx], Dr[idx]);
            }
            __syncthreads();
            // stable rank (desc exact w, asc index); winners scatter 1.0
            for (int j = tid; j < bandCnt; j += NT) {
                const unsigned int me = bandU[j];
                const int mi = bandIdxA[j];
                int rk = 0;
                for (int i = 0; i < bandCnt; i++) {
                    const unsigned int o = bandU[i];
                    rk += (int)((o > me) || (o == me && bandIdxA[i] < mi));
                }
                if (rk < kb2) OrU[mi] = ONE_BITS;
            }
            // candidates decisively above the band -> 1
            for (int j = tid; j < candCnt; j += NT)
                if (candKey[j] > band_hi_u) OrU[candIdx[j]] = ONE_BITS;
            return;
        }
    }

    // ================= exact fallback (uniform branch; ~1e-3 of dispatches) ==
    __syncthreads();
    for (int i = tid; i < 8192; i += NT) hist[i] = 0;
    __syncthreads();
#pragma unroll 1
    for (int J = 0; J < 16; ++J) {
        const int e = (J << 12) + (tid << 2);
        float4 u4 = *(const float4*)(Ur + e);
        float4 d4 = *(const float4*)(Dr + e);
        u32x4 kv;
        kv.x = wexact(u4.x, d4.x);
        kv.y = wexact(u4.y, d4.y);
        kv.z = wexact(u4.z, d4.z);
        kv.w = wexact(u4.w, d4.w);
        *(u32x4*)(OrU + e) = kv;
        atomicAdd(&hist[kv.x >> 19], 1u);
        atomicAdd(&hist[kv.y >> 19], 1u);
        atomicAdd(&hist[kv.z >> 19], 1u);
        atomicAdd(&hist[kv.w >> 19], 1u);
    }
    __syncthreads();

    PASS1SEL(kk)
    const unsigned int q13 = s_sel;
    const unsigned int en1 = s_kneed;
    hist[tid] = 0;
    __syncthreads();
#pragma unroll 1
    for (int J = 0; J < 16; ++J) {
        const int e = (J << 12) + (tid << 2);
        u32x4 kv = *(const u32x4*)(OrU + e);
        if ((kv.x >> 19) == q13) atomicAdd(&hist[(kv.x >> 9) & 1023u], 1u);
        if ((kv.y >> 19) == q13) atomicAdd(&hist[(kv.y >> 9) & 1023u], 1u);
        if ((kv.z >> 19) == q13) atomicAdd(&hist[(kv.z >> 9) & 1023u], 1u);
        if ((kv.w >> 19) == q13) atomicAdd(&hist[(kv.w >> 9) & 1023u], 1u);
    }
    __syncthreads();
    PASS2SEL(q13, en1)

    const unsigned int q23 = s_sel;
    const unsigned int en2 = s_kneed;
    if (tid < 512) hist[tid] = 0;
    __syncthreads();
#pragma unroll 1
    for (int J = 0; J < 16; ++J) {
        const int e = (J << 12) + (tid << 2);
        u32x4 kv = *(const u32x4*)(OrU + e);
        if ((kv.x >> 9) == q23) atomicAdd(&hist[kv.x & 511u], 1u);
        if ((kv.y >> 9) == q23) atomicAdd(&hist[kv.y & 511u], 1u);
        if ((kv.z >> 9) == q23) atomicAdd(&hist[kv.z & 511u], 1u);
        if ((kv.w >> 9) == q23) atomicAdd(&hist[kv.w & 511u], 1u);
    }
    __syncthreads();
    PASS3SEL(q23, en2)

    const unsigned int theta = s_sel;
    const unsigned int kneedF = s_kneed, eqF = s_eq;
    const bool needOrder = (kneedF < eqF);
    int istar = NN;
    if (needOrder) {
        if (tid == 0) s_tiecnt = 0;
        __syncthreads();
#pragma unroll 1
        for (int J = 0; J < 16; ++J) {
            const int e = (J << 12) + (tid << 2);
            u32x4 kv = *(const u32x4*)(OrU + e);
#define TIEV(UU, EIDX) if ((UU) == theta) { \
                int pos = atomicAdd(&s_tiecnt, 1); \
                if (pos < 1024) tielist[pos] = (EIDX); }
            TIEV(kv.x, e + 0)
            TIEV(kv.y, e + 1)
            TIEV(kv.z, e + 2)
            TIEV(kv.w, e + 3)
#undef TIEV
        }
        __syncthreads();
        if (tid == 0) {
            int E = s_tiecnt; if (E > 1024) E = 1024;
            for (int aI = 1; aI < E; aI++) {
                int val = tielist[aI]; int bI = aI - 1;
                while (bI >= 0 && tielist[bI] > val) { tielist[bI + 1] = tielist[bI]; bI--; }
                tielist[bI + 1] = val;
            }
            int kk2 = (int)kneedF; if (kk2 > E) kk2 = E; if (kk2 < 1) kk2 = 1;
            s_tieidx = tielist[kk2 - 1];
        }
        __syncthreads();
        istar = s_tieidx;
    }

#pragma unroll 1
    for (int J = 0; J < 16; ++J) {
        const int e = (J << 12) + (tid << 2);
        u32x4 kv = *(const u32x4*)(OrU + e);
        u32x4 m;
#define MVE(u, idx) ((((u) > theta) || ((u) == theta && (!needOrder || (idx) <= istar))) ? ONE_BITS : 0u)
        m.x = MVE(kv.x, e + 0);
        m.y = MVE(kv.y, e + 1);
        m.z = MVE(kv.z, e + 2);
        m.w = MVE(kv.w, e + 3);
#undef MVE
        *(u32x4*)(OrU + e) = m;
    }
}

extern "C" void kernel_launch(void* const* d_in, const int* in_sizes, int n_in,
                              void* d_out, int out_size, void* d_ws, size_t ws_size,
                              hipStream_t stream) {
    // inputs: batch[B*N] i32 (unused), t[B] f32, U[B*N] f32, D[B*N] f32
    const float* T = (const float*)d_in[1];
    const float* U = (const float*)d_in[2];
    const float* D = (const float*)d_in[3];
    float* out = (float*)d_out;
    float* wout = out + (size_t)BB * NN;

    md_fused_kernel<<<BB, NT, 0, stream>>>(T, U, D, out, wout);
}